// Round 1
// baseline (1092.991 us; speedup 1.0000x reference)
//
#include <hip/hip_runtime.h>

typedef unsigned int u32;
typedef unsigned short u16;
typedef short bf16x8 __attribute__((ext_vector_type(8)));
typedef float f32x4 __attribute__((ext_vector_type(4)));
typedef u32 u32x4 __attribute__((ext_vector_type(4)));

__device__ __forceinline__ u16 f2bf(float f) {
  u32 u = __float_as_uint(f);
  u = (u + 0x7FFFu + ((u >> 16) & 1u)) >> 16;
  return (u16)u;
}
__device__ __forceinline__ float bf2f(u32 h) { return __uint_as_float(h << 16); }

// ---------------- CSR build ----------------
__global__ void count_kernel(const int* __restrict__ dst, int* cnt, int E) {
  int e = blockIdx.x * 256 + threadIdx.x;
  if (e < E) atomicAdd(&cnt[dst[e]], 1);
}

__global__ void scan_kernel(const int* __restrict__ cnt, int* __restrict__ roff, int n) {
  __shared__ int sums[256];
  __shared__ int carry;
  int tid = threadIdx.x;
  if (tid == 0) carry = 0;
  __syncthreads();
  const int CH = 64;
  for (int base = 0; base < n; base += 256 * CH) {
    int start = base + tid * CH;
    int loc[CH];
    int s = 0;
#pragma unroll
    for (int q = 0; q < CH; ++q) {
      int ii = start + q;
      int v = (ii < n) ? cnt[ii] : 0;
      loc[q] = s;
      s += v;
    }
    sums[tid] = s;
    __syncthreads();
    for (int off = 1; off < 256; off <<= 1) {
      int t = (tid >= off) ? sums[tid - off] : 0;
      __syncthreads();
      sums[tid] += t;
      __syncthreads();
    }
    int pre = carry + sums[tid] - s;
#pragma unroll
    for (int q = 0; q < CH; ++q) {
      int ii = start + q;
      if (ii < n) roff[ii] = pre + loc[q];
    }
    int total = sums[255];
    __syncthreads();
    if (tid == 0) carry += total;
    __syncthreads();
  }
  if (tid == 0) roff[n] = carry;
}

__global__ void scatter_kernel(const int* __restrict__ src, const int* __restrict__ dst,
                               const int* __restrict__ roff, int* cursor, int* csr, int E) {
  int e = blockIdx.x * 256 + threadIdx.x;
  if (e < E) {
    int d = dst[e];
    int pos = atomicAdd(&cursor[d], 1);
    csr[roff[d] + pos] = src[e];
  }
}

// ---------------- layer 1 (rank-2) ----------------
__global__ void mean1_kernel(const int* __restrict__ csr, const int* __restrict__ roff,
                             const float* __restrict__ x, float* __restrict__ mean1, int n) {
  int i = blockIdx.x * 256 + threadIdx.x;
  if (i >= n) return;
  int e0 = roff[i], e1 = roff[i + 1];
  float s = 0.f;
  for (int e = e0; e < e1; ++e) s += x[csr[e]];
  mean1[i] = s / (float)max(e1 - e0, 1);
}

__global__ void h1_kernel(const float* __restrict__ mean1, const float* __restrict__ x,
                          const float* __restrict__ W1l, const float* __restrict__ W1r,
                          const float* __restrict__ b1, u32* __restrict__ h1, int n) {
  int idx = blockIdx.x * 256 + threadIdx.x;  // over n*64 packed words
  if (idx >= n * 64) return;
  int i = idx >> 6, w = idx & 63;
  int j0 = w * 2;
  float m1 = mean1[i], xs = x[i];
  float v0 = fmaxf(m1 * W1l[j0] + xs * W1r[j0] + b1[j0], 0.f);
  float v1 = fmaxf(m1 * W1l[j0 + 1] + xs * W1r[j0 + 1] + b1[j0 + 1], 0.f);
  h1[idx] = (u32)f2bf(v0) | ((u32)f2bf(v1) << 16);
}

// agg of h1 over edges, with h1 recomputed from 2 scalars per edge (8B instead of 512B)
__global__ void agg2_kernel(const int* __restrict__ csr, const int* __restrict__ roff,
                            const float* __restrict__ mean1, const float* __restrict__ x,
                            const float* __restrict__ W1l, const float* __restrict__ W1r,
                            const float* __restrict__ b1, u32* __restrict__ outv, int n) {
  int wave = threadIdx.x >> 6, lane = threadIdx.x & 63;
  int i = blockIdx.x * 4 + wave;
  if (i >= n) return;
  int j0 = lane * 2;
  float wl0 = W1l[j0], wl1 = W1l[j0 + 1];
  float wr0 = W1r[j0], wr1 = W1r[j0 + 1];
  float bb0 = b1[j0], bb1 = b1[j0 + 1];
  int e0 = roff[i], e1 = roff[i + 1];
  float a0 = 0.f, a1 = 0.f;
  for (int e = e0; e < e1; ++e) {
    int s = csr[e];
    float m1 = mean1[s], xs = x[s];
    a0 += fmaxf(m1 * wl0 + xs * wr0 + bb0, 0.f);
    a1 += fmaxf(m1 * wl1 + xs * wr1 + bb1, 0.f);
  }
  float inv = 1.f / (float)max(e1 - e0, 1);
  outv[(size_t)i * 64 + lane] = (u32)f2bf(a0 * inv) | ((u32)f2bf(a1 * inv) << 16);
}

// generic feature aggregation: one wave per node, 256B coalesced row reads
__global__ void agg3_kernel(const int* __restrict__ csr, const int* __restrict__ roff,
                            const u32* __restrict__ hin, u32* __restrict__ outv, int n) {
  int wave = threadIdx.x >> 6, lane = threadIdx.x & 63;
  int i = blockIdx.x * 4 + wave;
  if (i >= n) return;
  int e0 = roff[i], e1 = roff[i + 1];
  float a0 = 0.f, a1 = 0.f;
  for (int e = e0; e < e1; ++e) {
    int s = csr[e];
    u32 v = hin[(size_t)s * 64 + lane];
    a0 += bf2f(v & 0xFFFFu);
    a1 += bf2f(v >> 16);
  }
  float inv = 1.f / (float)max(e1 - e0, 1);
  outv[(size_t)i * 64 + lane] = (u32)f2bf(a0 * inv) | ((u32)f2bf(a1 * inv) << 16);
}

// pack [W_l; W_r] (256x128 f32, row-major k x j) into bf16 W^T layout wt[j][k], j<128, k<256
__global__ void wprep_kernel(const float* __restrict__ Wl, const float* __restrict__ Wr,
                             u16* __restrict__ wt) {
  int idx = blockIdx.x * 256 + threadIdx.x;  // 0..32767
  int j = idx >> 8, k = idx & 255;
  float v = (k < 128) ? Wl[k * 128 + j] : Wr[(k - 128) * 128 + j];
  wt[idx] = f2bf(v);
}

// h_next = relu([mean | h] @ [Wl; Wr] + b), MFMA 16x16x32 bf16, in-place safe (per-wave rows)
__launch_bounds__(256)
__global__ void mm_kernel(const u16* Aleft, const u16* Aright,
                          const u16* __restrict__ Wt, const float* __restrict__ bias,
                          u16* Out, int n) {
  __shared__ u16 wlds[32768];  // [j][256], 16B chunks XOR-swizzled by j to kill bank conflicts
  for (int c = threadIdx.x; c < 4096; c += 256) {
    int j = c >> 5, ch = c & 31;
    int swz = ch ^ (j & 31);
    *(u32x4*)(&wlds[j * 256 + swz * 8]) = *(const u32x4*)(&Wt[j * 256 + ch * 8]);
  }
  __syncthreads();
  int wave = threadIdx.x >> 6;
  int lane = threadIdx.x & 63;
  int quad = lane >> 4, l16 = lane & 15;
  int row0 = blockIdx.x * 64 + wave * 16;
  int m = row0 + l16;
  int mc = m < n ? m : (n - 1);
  f32x4 acc[8] = {};
  const u16* Ah[2] = {Aleft, Aright};
#pragma unroll
  for (int half = 0; half < 2; ++half) {
    const u16* A = Ah[half] + (size_t)mc * 128;
#pragma unroll
    for (int s = 0; s < 4; ++s) {
      bf16x8 a = *(const bf16x8*)(A + s * 32 + quad * 8);  // A[m][k], k = s*32+quad*8+j
      int chunk = (half << 4) + (s << 2) + quad;
#pragma unroll
      for (int t = 0; t < 8; ++t) {
        int j = t * 16 + l16;
        int swz = chunk ^ (j & 31);
        bf16x8 b = *(const bf16x8*)(&wlds[j * 256 + swz * 8]);  // B[k][j] = Wt[j][k]
        acc[t] = __builtin_amdgcn_mfma_f32_16x16x32_bf16(a, b, acc[t], 0, 0, 0);
      }
    }
  }
  // C layout: col = lane&15, row = quad*4 + reg   (m89-verified)
#pragma unroll
  for (int t = 0; t < 8; ++t) {
    int j = t * 16 + l16;
    float bj = bias[j];
#pragma unroll
    for (int r = 0; r < 4; ++r) {
      int mr = row0 + quad * 4 + r;
      if (mr < n) {
        float v = acc[t][r] + bj;
        Out[(size_t)mr * 128 + j] = f2bf(fmaxf(v, 0.f));
      }
    }
  }
}

// mean-pool per graph (batch sorted -> binary search), FC 128->10, log_softmax
__global__ void poolhead_kernel(const int* __restrict__ batch, const u32* __restrict__ h3,
                                const float* __restrict__ Wfc, const float* __restrict__ bfc,
                                float* __restrict__ out, int n) {
  int g = blockIdx.x;
  int lane = threadIdx.x;  // 64 threads
  int lo = 0, hi = n;
  while (lo < hi) { int mid = (lo + hi) >> 1; if (batch[mid] < g) lo = mid + 1; else hi = mid; }
  int s = lo;
  int lo2 = s, hi2 = n;
  while (lo2 < hi2) { int mid = (lo2 + hi2) >> 1; if (batch[mid] < g + 1) lo2 = mid + 1; else hi2 = mid; }
  int e = lo2;
  float a0 = 0.f, a1 = 0.f;
  for (int i = s; i < e; ++i) {
    u32 v = h3[(size_t)i * 64 + lane];
    a0 += bf2f(v & 0xFFFFu);
    a1 += bf2f(v >> 16);
  }
  float inv = 1.f / (float)max(e - s, 1);
  a0 *= inv; a1 *= inv;
  __shared__ float pool[128];
  __shared__ float lg[10];
  pool[lane * 2] = a0;
  pool[lane * 2 + 1] = a1;
  __syncthreads();
  if (lane < 10) {
    float acc = bfc[lane];
    for (int k = 0; k < 128; ++k) acc += pool[k] * Wfc[k * 10 + lane];
    lg[lane] = acc;
  }
  __syncthreads();
  if (lane < 10) {
    float mx = -1e30f;
    for (int c = 0; c < 10; ++c) mx = fmaxf(mx, lg[c]);
    float se = 0.f;
    for (int c = 0; c < 10; ++c) se += expf(lg[c] - mx);
    out[g * 10 + lane] = lg[lane] - mx - logf(se);
  }
}

extern "C" void kernel_launch(void* const* d_in, const int* in_sizes, int n_in,
                              void* d_out, int out_size, void* d_ws, size_t ws_size,
                              hipStream_t stream) {
  const float* x   = (const float*)d_in[0];
  const int* ei    = (const int*)d_in[1];
  const int* batch = (const int*)d_in[2];
  const float* W1l = (const float*)d_in[3];
  const float* W1r = (const float*)d_in[4];
  const float* b1  = (const float*)d_in[5];
  const float* W2l = (const float*)d_in[6];
  const float* W2r = (const float*)d_in[7];
  const float* b2  = (const float*)d_in[8];
  const float* W3l = (const float*)d_in[9];
  const float* W3r = (const float*)d_in[10];
  const float* b3  = (const float*)d_in[11];
  const float* Wfc = (const float*)d_in[12];
  const float* bfc = (const float*)d_in[13];
  float* out = (float*)d_out;
  int N = in_sizes[0];
  int E = in_sizes[1] / 2;
  const int* src = ei;
  const int* dst = ei + E;

  char* p = (char*)d_ws;
  auto alloc = [&](size_t bytes) { void* r = (void*)p; p += (bytes + 255) & ~(size_t)255; return r; };
  int* cnt    = (int*)alloc((size_t)N * 4);
  int* roff   = (int*)alloc((size_t)(N + 1) * 4);
  int* cursor = (int*)alloc((size_t)N * 4);
  int* csr    = (int*)alloc((size_t)E * 4);
  float* mean1 = (float*)alloc((size_t)N * 4);
  u32* bufA   = (u32*)alloc((size_t)N * 64 * 4);  // h1 -> mean3 -> h3
  u32* bufB   = (u32*)alloc((size_t)N * 64 * 4);  // mean2 -> h2
  u16* wt2    = (u16*)alloc(32768 * 2);
  u16* wt3    = (u16*)alloc(32768 * 2);

  hipMemsetAsync(cnt, 0, (size_t)N * 4, stream);
  hipMemsetAsync(cursor, 0, (size_t)N * 4, stream);
  count_kernel<<<(E + 255) / 256, 256, 0, stream>>>(dst, cnt, E);
  scan_kernel<<<1, 256, 0, stream>>>(cnt, roff, N);
  scatter_kernel<<<(E + 255) / 256, 256, 0, stream>>>(src, dst, roff, cursor, csr, E);
  wprep_kernel<<<128, 256, 0, stream>>>(W2l, W2r, wt2);
  wprep_kernel<<<128, 256, 0, stream>>>(W3l, W3r, wt3);
  mean1_kernel<<<(N + 255) / 256, 256, 0, stream>>>(csr, roff, x, mean1, N);
  h1_kernel<<<((size_t)N * 64 + 255) / 256, 256, 0, stream>>>(mean1, x, W1l, W1r, b1, bufA, N);
  agg2_kernel<<<(N + 3) / 4, 256, 0, stream>>>(csr, roff, mean1, x, W1l, W1r, b1, bufB, N);
  mm_kernel<<<(N + 63) / 64, 256, 0, stream>>>((const u16*)bufB, (const u16*)bufA, wt2, b2, (u16*)bufB, N);
  agg3_kernel<<<(N + 3) / 4, 256, 0, stream>>>(csr, roff, bufB, bufA, N);
  mm_kernel<<<(N + 63) / 64, 256, 0, stream>>>((const u16*)bufA, (const u16*)bufB, wt3, b3, (u16*)bufA, N);
  poolhead_kernel<<<64, 64, 0, stream>>>(batch, bufA, Wfc, bfc, out, N);
}

// Round 2
// 749.766 us; speedup vs baseline: 1.4578x; 1.4578x over previous
//
#include <hip/hip_runtime.h>

typedef unsigned int u32;
typedef unsigned short u16;
typedef short bf16x8 __attribute__((ext_vector_type(8)));
typedef float f32x4 __attribute__((ext_vector_type(4)));
typedef u32 u32x4 __attribute__((ext_vector_type(4)));

__device__ __forceinline__ u16 f2bf(float f) {
  u32 u = __float_as_uint(f);
  u = (u + 0x7FFFu + ((u >> 16) & 1u)) >> 16;
  return (u16)u;
}
__device__ __forceinline__ float bf2f(u32 h) { return __uint_as_float(h << 16); }

// ---------------- CSR build ----------------
__global__ void count_kernel(const int* __restrict__ dst, int* cnt, int E) {
  int e = blockIdx.x * 256 + threadIdx.x;
  if (e < E) atomicAdd(&cnt[dst[e]], 1);
}

__global__ void scan_kernel(const int* __restrict__ cnt, int* __restrict__ roff, int n) {
  __shared__ int sums[256];
  __shared__ int carry;
  int tid = threadIdx.x;
  if (tid == 0) carry = 0;
  __syncthreads();
  const int CH = 64;
  for (int base = 0; base < n; base += 256 * CH) {
    int start = base + tid * CH;
    int loc[CH];
    int s = 0;
#pragma unroll
    for (int q = 0; q < CH; ++q) {
      int ii = start + q;
      int v = (ii < n) ? cnt[ii] : 0;
      loc[q] = s;
      s += v;
    }
    sums[tid] = s;
    __syncthreads();
    for (int off = 1; off < 256; off <<= 1) {
      int t = (tid >= off) ? sums[tid - off] : 0;
      __syncthreads();
      sums[tid] += t;
      __syncthreads();
    }
    int pre = carry + sums[tid] - s;
#pragma unroll
    for (int q = 0; q < CH; ++q) {
      int ii = start + q;
      if (ii < n) roff[ii] = pre + loc[q];
    }
    int total = sums[255];
    __syncthreads();
    if (tid == 0) carry += total;
    __syncthreads();
  }
  if (tid == 0) roff[n] = carry;
}

__global__ void scatter_kernel(const int* __restrict__ src, const int* __restrict__ dst,
                               const int* __restrict__ roff, int* cursor, int* csr, int E) {
  int e = blockIdx.x * 256 + threadIdx.x;
  if (e < E) {
    int d = dst[e];
    int pos = atomicAdd(&cursor[d], 1);
    csr[roff[d] + pos] = src[e];
  }
}

// ---------------- layer 1 (rank-2) ----------------
__global__ void mean1_kernel(const int* __restrict__ csr, const int* __restrict__ roff,
                             const float* __restrict__ x, float* __restrict__ mean1, int n) {
  int i = blockIdx.x * 256 + threadIdx.x;
  if (i >= n) return;
  int e0 = roff[i], e1 = roff[i + 1];
  float s = 0.f;
  for (int e = e0; e < e1; ++e) s += x[csr[e]];
  mean1[i] = s / (float)max(e1 - e0, 1);
}

__global__ void h1_kernel(const float* __restrict__ mean1, const float* __restrict__ x,
                          const float* __restrict__ W1l, const float* __restrict__ W1r,
                          const float* __restrict__ b1, u32* __restrict__ h1, int n) {
  int idx = blockIdx.x * 256 + threadIdx.x;  // over n*64 packed words
  if (idx >= n * 64) return;
  int i = idx >> 6, w = idx & 63;
  int j0 = w * 2;
  float m1 = mean1[i], xs = x[i];
  float v0 = fmaxf(m1 * W1l[j0] + xs * W1r[j0] + b1[j0], 0.f);
  float v1 = fmaxf(m1 * W1l[j0 + 1] + xs * W1r[j0 + 1] + b1[j0 + 1], 0.f);
  h1[idx] = (u32)f2bf(v0) | ((u32)f2bf(v1) << 16);
}

// agg of h1 over edges, with h1 recomputed from 2 scalars per edge (8B instead of 512B)
__global__ void agg2_kernel(const int* __restrict__ csr, const int* __restrict__ roff,
                            const float* __restrict__ mean1, const float* __restrict__ x,
                            const float* __restrict__ W1l, const float* __restrict__ W1r,
                            const float* __restrict__ b1, u32* __restrict__ outv, int n) {
  int wave = threadIdx.x >> 6, lane = threadIdx.x & 63;
  int i = blockIdx.x * 4 + wave;
  if (i >= n) return;
  int j0 = lane * 2;
  float wl0 = W1l[j0], wl1 = W1l[j0 + 1];
  float wr0 = W1r[j0], wr1 = W1r[j0 + 1];
  float bb0 = b1[j0], bb1 = b1[j0 + 1];
  int e0 = roff[i], e1 = roff[i + 1];
  float a0 = 0.f, a1 = 0.f;
  for (int e = e0; e < e1; ++e) {
    int s = csr[e];
    float m1 = mean1[s], xs = x[s];
    a0 += fmaxf(m1 * wl0 + xs * wr0 + bb0, 0.f);
    a1 += fmaxf(m1 * wl1 + xs * wr1 + bb1, 0.f);
  }
  float inv = 1.f / (float)max(e1 - e0, 1);
  outv[(size_t)i * 64 + lane] = (u32)f2bf(a0 * inv) | ((u32)f2bf(a1 * inv) << 16);
}

// generic feature aggregation: one wave per node, 256B coalesced row reads
__global__ void agg3_kernel(const int* __restrict__ csr, const int* __restrict__ roff,
                            const u32* __restrict__ hin, u32* __restrict__ outv, int n) {
  int wave = threadIdx.x >> 6, lane = threadIdx.x & 63;
  int i = blockIdx.x * 4 + wave;
  if (i >= n) return;
  int e0 = roff[i], e1 = roff[i + 1];
  float a0 = 0.f, a1 = 0.f;
  for (int e = e0; e < e1; ++e) {
    int s = csr[e];
    u32 v = hin[(size_t)s * 64 + lane];
    a0 += bf2f(v & 0xFFFFu);
    a1 += bf2f(v >> 16);
  }
  float inv = 1.f / (float)max(e1 - e0, 1);
  outv[(size_t)i * 64 + lane] = (u32)f2bf(a0 * inv) | ((u32)f2bf(a1 * inv) << 16);
}

// pack [W_l; W_r] (256x128 f32, row-major k x j) into bf16 W^T layout wt[j][k], j<128, k<256
__global__ void wprep_kernel(const float* __restrict__ Wl, const float* __restrict__ Wr,
                             u16* __restrict__ wt) {
  int idx = blockIdx.x * 256 + threadIdx.x;  // 0..32767
  int j = idx >> 8, k = idx & 255;
  float v = (k < 128) ? Wl[k * 128 + j] : Wr[(k - 128) * 128 + j];
  wt[idx] = f2bf(v);
}

// h_next = relu([mean | h] @ [Wl; Wr] + b), MFMA 16x16x32 bf16, in-place safe (per-wave rows)
__launch_bounds__(256)
__global__ void mm_kernel(const u16* Aleft, const u16* Aright,
                          const u16* __restrict__ Wt, const float* __restrict__ bias,
                          u16* Out, int n) {
  __shared__ u16 wlds[32768];  // [j][256], 16B chunks XOR-swizzled by j to kill bank conflicts
  for (int c = threadIdx.x; c < 4096; c += 256) {
    int j = c >> 5, ch = c & 31;
    int swz = ch ^ (j & 31);
    *(u32x4*)(&wlds[j * 256 + swz * 8]) = *(const u32x4*)(&Wt[j * 256 + ch * 8]);
  }
  __syncthreads();
  int wave = threadIdx.x >> 6;
  int lane = threadIdx.x & 63;
  int quad = lane >> 4, l16 = lane & 15;
  int row0 = blockIdx.x * 64 + wave * 16;
  int m = row0 + l16;
  int mc = m < n ? m : (n - 1);
  f32x4 acc[8] = {};
  const u16* Ah[2] = {Aleft, Aright};
#pragma unroll
  for (int half = 0; half < 2; ++half) {
    const u16* A = Ah[half] + (size_t)mc * 128;
#pragma unroll
    for (int s = 0; s < 4; ++s) {
      bf16x8 a = *(const bf16x8*)(A + s * 32 + quad * 8);  // A[m][k], k = s*32+quad*8+j
      int chunk = (half << 4) + (s << 2) + quad;
#pragma unroll
      for (int t = 0; t < 8; ++t) {
        int j = t * 16 + l16;
        int swz = chunk ^ (j & 31);
        bf16x8 b = *(const bf16x8*)(&wlds[j * 256 + swz * 8]);  // B[k][j] = Wt[j][k]
        acc[t] = __builtin_amdgcn_mfma_f32_16x16x32_bf16(a, b, acc[t], 0, 0, 0);
      }
    }
  }
  // C layout: col = lane&15, row = quad*4 + reg   (m89-verified)
#pragma unroll
  for (int t = 0; t < 8; ++t) {
    int j = t * 16 + l16;
    float bj = bias[j];
#pragma unroll
    for (int r = 0; r < 4; ++r) {
      int mr = row0 + quad * 4 + r;
      if (mr < n) {
        float v = acc[t][r] + bj;
        Out[(size_t)mr * 128 + j] = f2bf(fmaxf(v, 0.f));
      }
    }
  }
}

// ---------------- pooling (two-phase, parallel) ----------------
// Phase 1: waves accumulate contiguous sorted-batch node slices in registers,
// flush to global accumulators only at graph boundaries.
#define PB_NODES 256
__global__ void pool_partial(const int* __restrict__ batch, const u32* __restrict__ h3,
                             float* __restrict__ pooled, int* __restrict__ gcnt, int n) {
  int wave = threadIdx.x >> 6, lane = threadIdx.x & 63;
  int start = blockIdx.x * PB_NODES;
  int end = min(start + PB_NODES, n);
  float a0 = 0.f, a1 = 0.f;
  int gcur = -1, cnt = 0;
  for (int i = start + wave; i < end; i += 4) {
    int g = batch[i];  // wave-uniform broadcast load (sorted batch, same i per wave)
    if (g != gcur) {
      if (gcur >= 0) {
        atomicAdd(&pooled[gcur * 128 + lane * 2], a0);
        atomicAdd(&pooled[gcur * 128 + lane * 2 + 1], a1);
        if (lane == 0) atomicAdd(&gcnt[gcur], cnt);
      }
      gcur = g; a0 = 0.f; a1 = 0.f; cnt = 0;
    }
    u32 v = h3[(size_t)i * 64 + lane];
    a0 += bf2f(v & 0xFFFFu);
    a1 += bf2f(v >> 16);
    cnt++;
  }
  if (gcur >= 0) {
    atomicAdd(&pooled[gcur * 128 + lane * 2], a0);
    atomicAdd(&pooled[gcur * 128 + lane * 2 + 1], a1);
    if (lane == 0) atomicAdd(&gcnt[gcur], cnt);
  }
}

// Phase 2: mean + FC(128->10) + log_softmax. One block, 640 threads (g,c) pairs.
__global__ void head_kernel(const float* __restrict__ pooled, const int* __restrict__ gcnt,
                            const float* __restrict__ Wfc, const float* __restrict__ bfc,
                            float* __restrict__ out) {
  __shared__ float lg[64][10];
  int t = threadIdx.x;
  if (t < 640) {
    int g = t / 10, c = t % 10;
    float inv = 1.f / (float)max(gcnt[g], 1);
    float acc = bfc[c];
    for (int k = 0; k < 128; ++k) acc += pooled[g * 128 + k] * inv * Wfc[k * 10 + c];
    lg[g][c] = acc;
  }
  __syncthreads();
  if (t < 640) {
    int g = t / 10, c = t % 10;
    float mx = -1e30f;
    for (int q = 0; q < 10; ++q) mx = fmaxf(mx, lg[g][q]);
    float se = 0.f;
    for (int q = 0; q < 10; ++q) se += expf(lg[g][q] - mx);
    out[g * 10 + c] = lg[g][c] - mx - logf(se);
  }
}

extern "C" void kernel_launch(void* const* d_in, const int* in_sizes, int n_in,
                              void* d_out, int out_size, void* d_ws, size_t ws_size,
                              hipStream_t stream) {
  const float* x   = (const float*)d_in[0];
  const int* ei    = (const int*)d_in[1];
  const int* batch = (const int*)d_in[2];
  const float* W1l = (const float*)d_in[3];
  const float* W1r = (const float*)d_in[4];
  const float* b1  = (const float*)d_in[5];
  const float* W2l = (const float*)d_in[6];
  const float* W2r = (const float*)d_in[7];
  const float* b2  = (const float*)d_in[8];
  const float* W3l = (const float*)d_in[9];
  const float* W3r = (const float*)d_in[10];
  const float* b3  = (const float*)d_in[11];
  const float* Wfc = (const float*)d_in[12];
  const float* bfc = (const float*)d_in[13];
  float* out = (float*)d_out;
  int N = in_sizes[0];
  int E = in_sizes[1] / 2;
  const int* src = ei;
  const int* dst = ei + E;

  char* p = (char*)d_ws;
  auto alloc = [&](size_t bytes) { void* r = (void*)p; p += (bytes + 255) & ~(size_t)255; return r; };
  int* cnt    = (int*)alloc((size_t)N * 4);
  int* roff   = (int*)alloc((size_t)(N + 1) * 4);
  int* cursor = (int*)alloc((size_t)N * 4);
  int* csr    = (int*)alloc((size_t)E * 4);
  float* mean1 = (float*)alloc((size_t)N * 4);
  u32* bufA   = (u32*)alloc((size_t)N * 64 * 4);  // h1 -> mean3 -> h3
  u32* bufB   = (u32*)alloc((size_t)N * 64 * 4);  // mean2 -> h2
  u16* wt2    = (u16*)alloc(32768 * 2);
  u16* wt3    = (u16*)alloc(32768 * 2);
  float* pooled = (float*)alloc(64 * 128 * 4);
  int* gcnt   = (int*)alloc(64 * 4);

  hipMemsetAsync(cnt, 0, (size_t)N * 4, stream);
  hipMemsetAsync(cursor, 0, (size_t)N * 4, stream);
  hipMemsetAsync(pooled, 0, 64 * 128 * 4, stream);
  hipMemsetAsync(gcnt, 0, 64 * 4, stream);
  count_kernel<<<(E + 255) / 256, 256, 0, stream>>>(dst, cnt, E);
  scan_kernel<<<1, 256, 0, stream>>>(cnt, roff, N);
  scatter_kernel<<<(E + 255) / 256, 256, 0, stream>>>(src, dst, roff, cursor, csr, E);
  wprep_kernel<<<128, 256, 0, stream>>>(W2l, W2r, wt2);
  wprep_kernel<<<128, 256, 0, stream>>>(W3l, W3r, wt3);
  mean1_kernel<<<(N + 255) / 256, 256, 0, stream>>>(csr, roff, x, mean1, N);
  h1_kernel<<<((size_t)N * 64 + 255) / 256, 256, 0, stream>>>(mean1, x, W1l, W1r, b1, bufA, N);
  agg2_kernel<<<(N + 3) / 4, 256, 0, stream>>>(csr, roff, mean1, x, W1l, W1r, b1, bufB, N);
  mm_kernel<<<(N + 63) / 64, 256, 0, stream>>>((const u16*)bufB, (const u16*)bufA, wt2, b2, (u16*)bufB, N);
  agg3_kernel<<<(N + 3) / 4, 256, 0, stream>>>(csr, roff, bufB, bufA, N);
  mm_kernel<<<(N + 63) / 64, 256, 0, stream>>>((const u16*)bufA, (const u16*)bufB, wt3, b3, (u16*)bufA, N);
  pool_partial<<<(N + PB_NODES - 1) / PB_NODES, 256, 0, stream>>>(batch, bufA, pooled, gcnt, N);
  head_kernel<<<1, 640, 0, stream>>>(pooled, gcnt, Wfc, bfc, out);
}

// Round 3
// 554.145 us; speedup vs baseline: 1.9724x; 1.3530x over previous
//
#include <hip/hip_runtime.h>

typedef unsigned int u32;
typedef unsigned short u16;
typedef short bf16x8 __attribute__((ext_vector_type(8)));
typedef float f32x4 __attribute__((ext_vector_type(4)));
typedef u32 u32x4 __attribute__((ext_vector_type(4)));

__device__ __forceinline__ u16 f2bf(float f) {
  u32 u = __float_as_uint(f);
  u = (u + 0x7FFFu + ((u >> 16) & 1u)) >> 16;
  return (u16)u;
}
__device__ __forceinline__ float bf2f(u32 h) { return __uint_as_float(h << 16); }

// ---------------- CSR build ----------------
__global__ void count_kernel(const int* __restrict__ dst, int* cnt, int E) {
  int e = blockIdx.x * 256 + threadIdx.x;
  if (e < E) atomicAdd(&cnt[dst[e]], 1);
}

// parallel scan: per-block local exclusive scan + block sums
__global__ void scan_local(const int* __restrict__ cnt, int* __restrict__ roff,
                           int* __restrict__ bsum, int n) {
  __shared__ int s[256];
  int tid = threadIdx.x;
  int i = blockIdx.x * 256 + tid;
  int v = (i < n) ? cnt[i] : 0;
  s[tid] = v;
  __syncthreads();
  for (int off = 1; off < 256; off <<= 1) {
    int t = (tid >= off) ? s[tid - off] : 0;
    __syncthreads();
    s[tid] += t;
    __syncthreads();
  }
  if (i < n) roff[i] = s[tid] - v;  // local exclusive
  if (tid == 255) bsum[blockIdx.x] = s[255];
}

// single block scans the (<=512) block sums in place -> exclusive
__global__ void scan_bsum(int* bsum, int nb) {
  __shared__ int s[512];
  int tid = threadIdx.x;
  int v = (tid < nb) ? bsum[tid] : 0;
  s[tid] = v;
  __syncthreads();
  for (int off = 1; off < 512; off <<= 1) {
    int t = (tid >= off) ? s[tid - off] : 0;
    __syncthreads();
    s[tid] += t;
    __syncthreads();
  }
  if (tid < nb) bsum[tid] = s[tid] - v;
}

__global__ void scan_add(int* __restrict__ roff, const int* __restrict__ bsum, int n, int E) {
  int i = blockIdx.x * 256 + threadIdx.x;
  if (i < n) roff[i] += bsum[blockIdx.x];
  if (i == 0) roff[n] = E;
}

__global__ void scatter_kernel(const int* __restrict__ src, const int* __restrict__ dst,
                               const int* __restrict__ roff, int* cursor, int* csr, int E) {
  int e = blockIdx.x * 256 + threadIdx.x;
  if (e < E) {
    int d = dst[e];
    int pos = atomicAdd(&cursor[d], 1);
    csr[roff[d] + pos] = src[e];
  }
}

// ---------------- layer 1 (rank-2) ----------------
__global__ void mean1_kernel(const int* __restrict__ csr, const int* __restrict__ roff,
                             const float* __restrict__ x, float* __restrict__ mean1, int n) {
  int i = blockIdx.x * 256 + threadIdx.x;
  if (i >= n) return;
  int e0 = roff[i], e1 = roff[i + 1];
  float s = 0.f;
  for (int e = e0; e < e1; ++e) s += x[csr[e]];
  mean1[i] = s / (float)max(e1 - e0, 1);
}

__global__ void h1_kernel(const float* __restrict__ mean1, const float* __restrict__ x,
                          const float* __restrict__ W1l, const float* __restrict__ W1r,
                          const float* __restrict__ b1, u32* __restrict__ h1, int n) {
  int idx = blockIdx.x * 256 + threadIdx.x;  // over n*64 packed words
  if (idx >= n * 64) return;
  int i = idx >> 6, w = idx & 63;
  int j0 = w * 2;
  float m1 = mean1[i], xs = x[i];
  float v0 = fmaxf(m1 * W1l[j0] + xs * W1r[j0] + b1[j0], 0.f);
  float v1 = fmaxf(m1 * W1l[j0 + 1] + xs * W1r[j0 + 1] + b1[j0 + 1], 0.f);
  h1[idx] = (u32)f2bf(v0) | ((u32)f2bf(v1) << 16);
}

// agg of h1 over edges, h1 recomputed from 2 scalars per edge; unrolled x4 for MLP
__global__ void agg2_kernel(const int* __restrict__ csr, const int* __restrict__ roff,
                            const float* __restrict__ mean1, const float* __restrict__ x,
                            const float* __restrict__ W1l, const float* __restrict__ W1r,
                            const float* __restrict__ b1, u32* __restrict__ outv, int n) {
  int wave = threadIdx.x >> 6, lane = threadIdx.x & 63;
  int i = blockIdx.x * 4 + wave;
  if (i >= n) return;
  int j0 = lane * 2;
  float wl0 = W1l[j0], wl1 = W1l[j0 + 1];
  float wr0 = W1r[j0], wr1 = W1r[j0 + 1];
  float bb0 = b1[j0], bb1 = b1[j0 + 1];
  int e0 = roff[i], e1 = roff[i + 1];
  float a0 = 0.f, a1 = 0.f;
  int e = e0;
  for (; e + 3 < e1; e += 4) {
    int s0 = csr[e], s1 = csr[e + 1], s2 = csr[e + 2], s3 = csr[e + 3];
    float m0 = mean1[s0], xs0 = x[s0];
    float m1 = mean1[s1], xs1 = x[s1];
    float m2 = mean1[s2], xs2 = x[s2];
    float m3 = mean1[s3], xs3 = x[s3];
    a0 += fmaxf(m0 * wl0 + xs0 * wr0 + bb0, 0.f) + fmaxf(m1 * wl0 + xs1 * wr0 + bb0, 0.f) +
          fmaxf(m2 * wl0 + xs2 * wr0 + bb0, 0.f) + fmaxf(m3 * wl0 + xs3 * wr0 + bb0, 0.f);
    a1 += fmaxf(m0 * wl1 + xs0 * wr1 + bb1, 0.f) + fmaxf(m1 * wl1 + xs1 * wr1 + bb1, 0.f) +
          fmaxf(m2 * wl1 + xs2 * wr1 + bb1, 0.f) + fmaxf(m3 * wl1 + xs3 * wr1 + bb1, 0.f);
  }
  for (; e < e1; ++e) {
    int s = csr[e];
    float m1v = mean1[s], xs = x[s];
    a0 += fmaxf(m1v * wl0 + xs * wr0 + bb0, 0.f);
    a1 += fmaxf(m1v * wl1 + xs * wr1 + bb1, 0.f);
  }
  float inv = 1.f / (float)max(e1 - e0, 1);
  outv[(size_t)i * 64 + lane] = (u32)f2bf(a0 * inv) | ((u32)f2bf(a1 * inv) << 16);
}

// generic feature aggregation: 4x16-lane groups each gather a different edge's
// 256B row via dwordx4 (4 rows per load inst), unrolled x2 -> 8 edges in flight.
__global__ void agg3_kernel(const int* __restrict__ csr, const int* __restrict__ roff,
                            const u32* __restrict__ hin, u32* __restrict__ outv, int n) {
  int wave = threadIdx.x >> 6, lane = threadIdx.x & 63;
  int i = blockIdx.x * 4 + wave;
  if (i >= n) return;
  int grp = lane >> 4, li = lane & 15;
  int e0 = roff[i], e1 = roff[i + 1];
  float a[8] = {};
  int e = e0 + grp;
  for (; e + 4 < e1; e += 8) {
    int s0 = csr[e];
    int s1 = csr[e + 4];
    u32x4 v0 = *(const u32x4*)(hin + (size_t)s0 * 64 + li * 4);
    u32x4 v1 = *(const u32x4*)(hin + (size_t)s1 * 64 + li * 4);
#pragma unroll
    for (int w = 0; w < 4; ++w) {
      a[2 * w]     += bf2f(v0[w] & 0xFFFFu) + bf2f(v1[w] & 0xFFFFu);
      a[2 * w + 1] += bf2f(v0[w] >> 16)     + bf2f(v1[w] >> 16);
    }
  }
  if (e < e1) {
    int s0 = csr[e];
    u32x4 v0 = *(const u32x4*)(hin + (size_t)s0 * 64 + li * 4);
#pragma unroll
    for (int w = 0; w < 4; ++w) {
      a[2 * w]     += bf2f(v0[w] & 0xFFFFu);
      a[2 * w + 1] += bf2f(v0[w] >> 16);
    }
  }
  // reduce across the 4 groups (lanes differing in bits 4,5)
#pragma unroll
  for (int w = 0; w < 8; ++w) {
    a[w] += __shfl_xor(a[w], 16, 64);
    a[w] += __shfl_xor(a[w], 32, 64);
  }
  if (grp == 0) {
    float inv = 1.f / (float)max(e1 - e0, 1);
    u32x4 o;
#pragma unroll
    for (int w = 0; w < 4; ++w)
      o[w] = (u32)f2bf(a[2 * w] * inv) | ((u32)f2bf(a[2 * w + 1] * inv) << 16);
    *(u32x4*)(outv + (size_t)i * 64 + li * 4) = o;
  }
}

// pack [W_l; W_r] (256x128 f32, row-major k x j) into bf16 W^T layout wt[j][k], j<128, k<256
__global__ void wprep_kernel(const float* __restrict__ Wl, const float* __restrict__ Wr,
                             u16* __restrict__ wt) {
  int idx = blockIdx.x * 256 + threadIdx.x;  // 0..32767
  int j = idx >> 8, k = idx & 255;
  float v = (k < 128) ? Wl[k * 128 + j] : Wr[(k - 128) * 128 + j];
  wt[idx] = f2bf(v);
}

// h_next = relu([mean | h] @ [Wl; Wr] + b), MFMA 16x16x32 bf16, in-place safe (per-wave rows)
__launch_bounds__(256)
__global__ void mm_kernel(const u16* Aleft, const u16* Aright,
                          const u16* __restrict__ Wt, const float* __restrict__ bias,
                          u16* Out, int n) {
  __shared__ u16 wlds[32768];  // [j][256], 16B chunks XOR-swizzled by j to kill bank conflicts
  for (int c = threadIdx.x; c < 4096; c += 256) {
    int j = c >> 5, ch = c & 31;
    int swz = ch ^ (j & 31);
    *(u32x4*)(&wlds[j * 256 + swz * 8]) = *(const u32x4*)(&Wt[j * 256 + ch * 8]);
  }
  __syncthreads();
  int wave = threadIdx.x >> 6;
  int lane = threadIdx.x & 63;
  int quad = lane >> 4, l16 = lane & 15;
  int row0 = blockIdx.x * 64 + wave * 16;
  int m = row0 + l16;
  int mc = m < n ? m : (n - 1);
  f32x4 acc[8] = {};
  const u16* Ah[2] = {Aleft, Aright};
#pragma unroll
  for (int half = 0; half < 2; ++half) {
    const u16* A = Ah[half] + (size_t)mc * 128;
#pragma unroll
    for (int s = 0; s < 4; ++s) {
      bf16x8 a = *(const bf16x8*)(A + s * 32 + quad * 8);  // A[m][k], k = s*32+quad*8+j
      int chunk = (half << 4) + (s << 2) + quad;
#pragma unroll
      for (int t = 0; t < 8; ++t) {
        int j = t * 16 + l16;
        int swz = chunk ^ (j & 31);
        bf16x8 b = *(const bf16x8*)(&wlds[j * 256 + swz * 8]);  // B[k][j] = Wt[j][k]
        acc[t] = __builtin_amdgcn_mfma_f32_16x16x32_bf16(a, b, acc[t], 0, 0, 0);
      }
    }
  }
  // C layout: col = lane&15, row = quad*4 + reg   (m89-verified)
#pragma unroll
  for (int t = 0; t < 8; ++t) {
    int j = t * 16 + l16;
    float bj = bias[j];
#pragma unroll
    for (int r = 0; r < 4; ++r) {
      int mr = row0 + quad * 4 + r;
      if (mr < n) {
        float v = acc[t][r] + bj;
        Out[(size_t)mr * 128 + j] = f2bf(fmaxf(v, 0.f));
      }
    }
  }
}

// ---------------- pooling (two-phase, parallel) ----------------
#define PB_NODES 256
__global__ void pool_partial(const int* __restrict__ batch, const u32* __restrict__ h3,
                             float* __restrict__ pooled, int* __restrict__ gcnt, int n) {
  int wave = threadIdx.x >> 6, lane = threadIdx.x & 63;
  int start = blockIdx.x * PB_NODES;
  int end = min(start + PB_NODES, n);
  float a0 = 0.f, a1 = 0.f;
  int gcur = -1, cnt = 0;
  for (int i = start + wave; i < end; i += 4) {
    int g = batch[i];
    if (g != gcur) {
      if (gcur >= 0) {
        atomicAdd(&pooled[gcur * 128 + lane * 2], a0);
        atomicAdd(&pooled[gcur * 128 + lane * 2 + 1], a1);
        if (lane == 0) atomicAdd(&gcnt[gcur], cnt);
      }
      gcur = g; a0 = 0.f; a1 = 0.f; cnt = 0;
    }
    u32 v = h3[(size_t)i * 64 + lane];
    a0 += bf2f(v & 0xFFFFu);
    a1 += bf2f(v >> 16);
    cnt++;
  }
  if (gcur >= 0) {
    atomicAdd(&pooled[gcur * 128 + lane * 2], a0);
    atomicAdd(&pooled[gcur * 128 + lane * 2 + 1], a1);
    if (lane == 0) atomicAdd(&gcnt[gcur], cnt);
  }
}

__global__ void head_kernel(const float* __restrict__ pooled, const int* __restrict__ gcnt,
                            const float* __restrict__ Wfc, const float* __restrict__ bfc,
                            float* __restrict__ out) {
  __shared__ float lg[64][10];
  int t = threadIdx.x;
  if (t < 640) {
    int g = t / 10, c = t % 10;
    float inv = 1.f / (float)max(gcnt[g], 1);
    float acc = bfc[c];
    for (int k = 0; k < 128; ++k) acc += pooled[g * 128 + k] * inv * Wfc[k * 10 + c];
    lg[g][c] = acc;
  }
  __syncthreads();
  if (t < 640) {
    int g = t / 10, c = t % 10;
    float mx = -1e30f;
    for (int q = 0; q < 10; ++q) mx = fmaxf(mx, lg[g][q]);
    float se = 0.f;
    for (int q = 0; q < 10; ++q) se += expf(lg[g][q] - mx);
    out[g * 10 + c] = lg[g][c] - mx - logf(se);
  }
}

extern "C" void kernel_launch(void* const* d_in, const int* in_sizes, int n_in,
                              void* d_out, int out_size, void* d_ws, size_t ws_size,
                              hipStream_t stream) {
  const float* x   = (const float*)d_in[0];
  const int* ei    = (const int*)d_in[1];
  const int* batch = (const int*)d_in[2];
  const float* W1l = (const float*)d_in[3];
  const float* W1r = (const float*)d_in[4];
  const float* b1  = (const float*)d_in[5];
  const float* W2l = (const float*)d_in[6];
  const float* W2r = (const float*)d_in[7];
  const float* b2  = (const float*)d_in[8];
  const float* W3l = (const float*)d_in[9];
  const float* W3r = (const float*)d_in[10];
  const float* b3  = (const float*)d_in[11];
  const float* Wfc = (const float*)d_in[12];
  const float* bfc = (const float*)d_in[13];
  float* out = (float*)d_out;
  int N = in_sizes[0];
  int E = in_sizes[1] / 2;
  const int* src = ei;
  const int* dst = ei + E;

  char* p = (char*)d_ws;
  auto alloc = [&](size_t bytes) { void* r = (void*)p; p += (bytes + 255) & ~(size_t)255; return r; };
  int* cnt    = (int*)alloc((size_t)N * 4);
  int* roff   = (int*)alloc((size_t)(N + 1) * 4);
  int* cursor = (int*)alloc((size_t)N * 4);
  int* csr    = (int*)alloc((size_t)E * 4);
  float* mean1 = (float*)alloc((size_t)N * 4);
  u32* bufA   = (u32*)alloc((size_t)N * 64 * 4);  // h1 -> mean3 -> h3
  u32* bufB   = (u32*)alloc((size_t)N * 64 * 4);  // mean2 -> h2
  u16* wt2    = (u16*)alloc(32768 * 2);
  u16* wt3    = (u16*)alloc(32768 * 2);
  float* pooled = (float*)alloc(64 * 128 * 4);
  int* gcnt   = (int*)alloc(64 * 4);
  int* bsum   = (int*)alloc(512 * 4);

  int nb = (N + 255) / 256;  // 391 <= 512
  hipMemsetAsync(cnt, 0, (size_t)N * 4, stream);
  hipMemsetAsync(cursor, 0, (size_t)N * 4, stream);
  hipMemsetAsync(pooled, 0, 64 * 128 * 4, stream);
  hipMemsetAsync(gcnt, 0, 64 * 4, stream);
  count_kernel<<<(E + 255) / 256, 256, 0, stream>>>(dst, cnt, E);
  scan_local<<<nb, 256, 0, stream>>>(cnt, roff, bsum, N);
  scan_bsum<<<1, 512, 0, stream>>>(bsum, nb);
  scan_add<<<nb, 256, 0, stream>>>(roff, bsum, N, E);
  scatter_kernel<<<(E + 255) / 256, 256, 0, stream>>>(src, dst, roff, cursor, csr, E);
  wprep_kernel<<<128, 256, 0, stream>>>(W2l, W2r, wt2);
  wprep_kernel<<<128, 256, 0, stream>>>(W3l, W3r, wt3);
  mean1_kernel<<<(N + 255) / 256, 256, 0, stream>>>(csr, roff, x, mean1, N);
  h1_kernel<<<((size_t)N * 64 + 255) / 256, 256, 0, stream>>>(mean1, x, W1l, W1r, b1, bufA, N);
  agg2_kernel<<<(N + 3) / 4, 256, 0, stream>>>(csr, roff, mean1, x, W1l, W1r, b1, bufB, N);
  mm_kernel<<<(N + 63) / 64, 256, 0, stream>>>((const u16*)bufB, (const u16*)bufA, wt2, b2, (u16*)bufB, N);
  agg3_kernel<<<(N + 3) / 4, 256, 0, stream>>>(csr, roff, bufB, bufA, N);
  mm_kernel<<<(N + 63) / 64, 256, 0, stream>>>((const u16*)bufA, (const u16*)bufB, wt3, b3, (u16*)bufA, N);
  pool_partial<<<(N + PB_NODES - 1) / PB_NODES, 256, 0, stream>>>(batch, bufA, pooled, gcnt, N);
  head_kernel<<<1, 640, 0, stream>>>(pooled, gcnt, Wfc, bfc, out);
}

// Round 4
// 421.093 us; speedup vs baseline: 2.5956x; 1.3160x over previous
//
#include <hip/hip_runtime.h>

typedef unsigned int u32;
typedef unsigned short u16;
typedef short bf16x8 __attribute__((ext_vector_type(8)));
typedef float f32x4 __attribute__((ext_vector_type(4)));
typedef u32 u32x4 __attribute__((ext_vector_type(4)));

#define HBLK 256  // blocks in hist/scatter2 pass

__device__ __forceinline__ u16 f2bf(float f) {
  u32 u = __float_as_uint(f);
  u = (u + 0x7FFFu + ((u >> 16) & 1u)) >> 16;
  return (u16)u;
}
__device__ __forceinline__ float bf2f(u32 h) { return __uint_as_float(h << 16); }

// ---------------- CSR build: bucket sort by dst ----------------
// bucket = dst >> 7 (128 nodes per bucket)
__global__ void hist_kernel(const int* __restrict__ dst, int* __restrict__ hist,
                            int E, int nbuk, int chunk) {
  __shared__ int h[1024];
  for (int i = threadIdx.x; i < nbuk; i += 256) h[i] = 0;
  __syncthreads();
  int b0 = blockIdx.x * chunk, b1 = min(b0 + chunk, E);
  for (int e = b0 + threadIdx.x; e < b1; e += 256)
    atomicAdd(&h[dst[e] >> 7], 1);
  __syncthreads();
  for (int i = threadIdx.x; i < nbuk; i += 256)
    hist[i * HBLK + blockIdx.x] = h[i];  // [bucket][block]
}

// generic parallel scan (exclusive), 3 launches
__global__ void scan_local(const int* __restrict__ in, int* __restrict__ out,
                           int* __restrict__ bsum, int n) {
  __shared__ int s[256];
  int tid = threadIdx.x;
  int i = blockIdx.x * 256 + tid;
  int v = (i < n) ? in[i] : 0;
  s[tid] = v;
  __syncthreads();
  for (int off = 1; off < 256; off <<= 1) {
    int t = (tid >= off) ? s[tid - off] : 0;
    __syncthreads();
    s[tid] += t;
    __syncthreads();
  }
  if (i < n) out[i] = s[tid] - v;  // local exclusive
  if (tid == 255) bsum[blockIdx.x] = s[255];
}

__global__ void scan_bsum(int* bsum, int nb) {
  __shared__ int s[1024];
  int tid = threadIdx.x;
  int v = (tid < nb) ? bsum[tid] : 0;
  s[tid] = v;
  __syncthreads();
  for (int off = 1; off < 1024; off <<= 1) {
    int t = (tid >= off) ? s[tid - off] : 0;
    __syncthreads();
    s[tid] += t;
    __syncthreads();
  }
  if (tid < nb) bsum[tid] = s[tid] - v;
}

__global__ void scan_add(int* __restrict__ a, const int* __restrict__ bsum, int n) {
  int i = blockIdx.x * 256 + threadIdx.x;
  if (i < n) a[i] += bsum[blockIdx.x];
}

// partition edges into bucket-ordered part[]: packed (dstLow7<<25 | src)
__global__ void scatter2_kernel(const int* __restrict__ src, const int* __restrict__ dst,
                                const int* __restrict__ hist_s, u32* __restrict__ part,
                                int E, int nbuk, int chunk) {
  __shared__ int cur[1024];
  for (int i = threadIdx.x; i < nbuk; i += 256)
    cur[i] = hist_s[i * HBLK + blockIdx.x];
  __syncthreads();
  int b0 = blockIdx.x * chunk, b1 = min(b0 + chunk, E);
  for (int e = b0 + threadIdx.x; e < b1; e += 256) {
    int d = dst[e];
    int pos = atomicAdd(&cur[d >> 7], 1);
    part[pos] = (u32)src[e] | ((u32)(d & 127) << 25);
  }
}

// per-bucket: count per node, scan -> roff, scatter src into contiguous csr window
__global__ void scatter3_kernel(const u32* __restrict__ part, const int* __restrict__ hist_s,
                                int* __restrict__ roff, int* __restrict__ csr,
                                int E, int nbuk, int n) {
  int b = blockIdx.x;
  int tid = threadIdx.x;
  int base = hist_s[b * HBLK];
  int end = (b + 1 < nbuk) ? hist_s[(b + 1) * HBLK] : E;
  __shared__ int cnt[128];
  __shared__ int s[128];
  __shared__ int cur[128];
  if (tid < 128) cnt[tid] = 0;
  __syncthreads();
  for (int e = base + tid; e < end; e += 256)
    atomicAdd(&cnt[part[e] >> 25], 1);
  __syncthreads();
  if (tid < 128) s[tid] = cnt[tid];
  __syncthreads();
  for (int off = 1; off < 128; off <<= 1) {
    int t = (tid >= off && tid < 128) ? s[tid - off] : 0;
    __syncthreads();
    if (tid < 128) s[tid] += t;
    __syncthreads();
  }
  if (tid < 128) {
    int excl = s[tid] - cnt[tid];
    cur[tid] = base + excl;
    int node = b * 128 + tid;
    if (node < n) roff[node] = base + excl;
  }
  if (b == 0 && tid == 0) roff[n] = E;
  __syncthreads();
  for (int e = base + tid; e < end; e += 256) {
    u32 p = part[e];
    int pos = atomicAdd(&cur[p >> 25], 1);
    csr[pos] = (int)(p & 0x1FFFFFFu);
  }
}

// ---------------- layer 1 (rank-2) ----------------
__global__ void mean1_kernel(const int* __restrict__ csr, const int* __restrict__ roff,
                             const float* __restrict__ x, float* __restrict__ mean1, int n) {
  int i = blockIdx.x * 256 + threadIdx.x;
  if (i >= n) return;
  int e0 = roff[i], e1 = roff[i + 1];
  float s = 0.f;
  for (int e = e0; e < e1; ++e) s += x[csr[e]];
  mean1[i] = s / (float)max(e1 - e0, 1);
}

__global__ void h1_kernel(const float* __restrict__ mean1, const float* __restrict__ x,
                          const float* __restrict__ W1l, const float* __restrict__ W1r,
                          const float* __restrict__ b1, u32* __restrict__ h1, int n) {
  int idx = blockIdx.x * 256 + threadIdx.x;  // over n*64 packed words
  if (idx >= n * 64) return;
  int i = idx >> 6, w = idx & 63;
  int j0 = w * 2;
  float m1 = mean1[i], xs = x[i];
  float v0 = fmaxf(m1 * W1l[j0] + xs * W1r[j0] + b1[j0], 0.f);
  float v1 = fmaxf(m1 * W1l[j0 + 1] + xs * W1r[j0 + 1] + b1[j0 + 1], 0.f);
  h1[idx] = (u32)f2bf(v0) | ((u32)f2bf(v1) << 16);
}

// agg of h1 over edges, h1 recomputed from 2 scalars per edge; unrolled x4 for MLP
__global__ void agg2_kernel(const int* __restrict__ csr, const int* __restrict__ roff,
                            const float* __restrict__ mean1, const float* __restrict__ x,
                            const float* __restrict__ W1l, const float* __restrict__ W1r,
                            const float* __restrict__ b1, u32* __restrict__ outv, int n) {
  int wave = threadIdx.x >> 6, lane = threadIdx.x & 63;
  int i = blockIdx.x * 4 + wave;
  if (i >= n) return;
  int j0 = lane * 2;
  float wl0 = W1l[j0], wl1 = W1l[j0 + 1];
  float wr0 = W1r[j0], wr1 = W1r[j0 + 1];
  float bb0 = b1[j0], bb1 = b1[j0 + 1];
  int e0 = roff[i], e1 = roff[i + 1];
  float a0 = 0.f, a1 = 0.f;
  int e = e0;
  for (; e + 3 < e1; e += 4) {
    int s0 = csr[e], s1 = csr[e + 1], s2 = csr[e + 2], s3 = csr[e + 3];
    float m0 = mean1[s0], xs0 = x[s0];
    float m1 = mean1[s1], xs1 = x[s1];
    float m2 = mean1[s2], xs2 = x[s2];
    float m3 = mean1[s3], xs3 = x[s3];
    a0 += fmaxf(m0 * wl0 + xs0 * wr0 + bb0, 0.f) + fmaxf(m1 * wl0 + xs1 * wr0 + bb0, 0.f) +
          fmaxf(m2 * wl0 + xs2 * wr0 + bb0, 0.f) + fmaxf(m3 * wl0 + xs3 * wr0 + bb0, 0.f);
    a1 += fmaxf(m0 * wl1 + xs0 * wr1 + bb1, 0.f) + fmaxf(m1 * wl1 + xs1 * wr1 + bb1, 0.f) +
          fmaxf(m2 * wl1 + xs2 * wr1 + bb1, 0.f) + fmaxf(m3 * wl1 + xs3 * wr1 + bb1, 0.f);
  }
  for (; e < e1; ++e) {
    int s = csr[e];
    float m1v = mean1[s], xs = x[s];
    a0 += fmaxf(m1v * wl0 + xs * wr0 + bb0, 0.f);
    a1 += fmaxf(m1v * wl1 + xs * wr1 + bb1, 0.f);
  }
  float inv = 1.f / (float)max(e1 - e0, 1);
  outv[(size_t)i * 64 + lane] = (u32)f2bf(a0 * inv) | ((u32)f2bf(a1 * inv) << 16);
}

// generic feature aggregation: 4x16-lane groups each gather a different edge's
// 256B row via dwordx4 (4 rows per load inst), unrolled x2 -> 8 edges in flight.
__global__ void agg3_kernel(const int* __restrict__ csr, const int* __restrict__ roff,
                            const u32* __restrict__ hin, u32* __restrict__ outv, int n) {
  int wave = threadIdx.x >> 6, lane = threadIdx.x & 63;
  int i = blockIdx.x * 4 + wave;
  if (i >= n) return;
  int grp = lane >> 4, li = lane & 15;
  int e0 = roff[i], e1 = roff[i + 1];
  float a[8] = {};
  int e = e0 + grp;
  for (; e + 4 < e1; e += 8) {
    int s0 = csr[e];
    int s1 = csr[e + 4];
    u32x4 v0 = *(const u32x4*)(hin + (size_t)s0 * 64 + li * 4);
    u32x4 v1 = *(const u32x4*)(hin + (size_t)s1 * 64 + li * 4);
#pragma unroll
    for (int w = 0; w < 4; ++w) {
      a[2 * w]     += bf2f(v0[w] & 0xFFFFu) + bf2f(v1[w] & 0xFFFFu);
      a[2 * w + 1] += bf2f(v0[w] >> 16)     + bf2f(v1[w] >> 16);
    }
  }
  if (e < e1) {
    int s0 = csr[e];
    u32x4 v0 = *(const u32x4*)(hin + (size_t)s0 * 64 + li * 4);
#pragma unroll
    for (int w = 0; w < 4; ++w) {
      a[2 * w]     += bf2f(v0[w] & 0xFFFFu);
      a[2 * w + 1] += bf2f(v0[w] >> 16);
    }
  }
#pragma unroll
  for (int w = 0; w < 8; ++w) {
    a[w] += __shfl_xor(a[w], 16, 64);
    a[w] += __shfl_xor(a[w], 32, 64);
  }
  if (grp == 0) {
    float inv = 1.f / (float)max(e1 - e0, 1);
    u32x4 o;
#pragma unroll
    for (int w = 0; w < 4; ++w)
      o[w] = (u32)f2bf(a[2 * w] * inv) | ((u32)f2bf(a[2 * w + 1] * inv) << 16);
    *(u32x4*)(outv + (size_t)i * 64 + li * 4) = o;
  }
}

// pack [W_l; W_r] (256x128 f32, row-major k x j) into bf16 W^T layout wt[j][k], j<128, k<256
__global__ void wprep_kernel(const float* __restrict__ Wl, const float* __restrict__ Wr,
                             u16* __restrict__ wt) {
  int idx = blockIdx.x * 256 + threadIdx.x;  // 0..32767
  int j = idx >> 8, k = idx & 255;
  float v = (k < 128) ? Wl[k * 128 + j] : Wr[(k - 128) * 128 + j];
  wt[idx] = f2bf(v);
}

// h_next = relu([mean | h] @ [Wl; Wr] + b), MFMA 16x16x32 bf16, in-place safe (per-wave rows)
__launch_bounds__(256)
__global__ void mm_kernel(const u16* Aleft, const u16* Aright,
                          const u16* __restrict__ Wt, const float* __restrict__ bias,
                          u16* Out, int n) {
  __shared__ u16 wlds[32768];  // [j][256], 16B chunks XOR-swizzled by j
  for (int c = threadIdx.x; c < 4096; c += 256) {
    int j = c >> 5, ch = c & 31;
    int swz = ch ^ (j & 31);
    *(u32x4*)(&wlds[j * 256 + swz * 8]) = *(const u32x4*)(&Wt[j * 256 + ch * 8]);
  }
  __syncthreads();
  int wave = threadIdx.x >> 6;
  int lane = threadIdx.x & 63;
  int quad = lane >> 4, l16 = lane & 15;
  int row0 = blockIdx.x * 64 + wave * 16;
  int m = row0 + l16;
  int mc = m < n ? m : (n - 1);
  f32x4 acc[8] = {};
  const u16* Ah[2] = {Aleft, Aright};
#pragma unroll
  for (int half = 0; half < 2; ++half) {
    const u16* A = Ah[half] + (size_t)mc * 128;
#pragma unroll
    for (int s = 0; s < 4; ++s) {
      bf16x8 a = *(const bf16x8*)(A + s * 32 + quad * 8);
      int chunk = (half << 4) + (s << 2) + quad;
#pragma unroll
      for (int t = 0; t < 8; ++t) {
        int j = t * 16 + l16;
        int swz = chunk ^ (j & 31);
        bf16x8 b = *(const bf16x8*)(&wlds[j * 256 + swz * 8]);
        acc[t] = __builtin_amdgcn_mfma_f32_16x16x32_bf16(a, b, acc[t], 0, 0, 0);
      }
    }
  }
#pragma unroll
  for (int t = 0; t < 8; ++t) {
    int j = t * 16 + l16;
    float bj = bias[j];
#pragma unroll
    for (int r = 0; r < 4; ++r) {
      int mr = row0 + quad * 4 + r;
      if (mr < n) {
        float v = acc[t][r] + bj;
        Out[(size_t)mr * 128 + j] = f2bf(fmaxf(v, 0.f));
      }
    }
  }
}

// ---------------- pooling (two-phase, parallel) ----------------
#define PB_NODES 256
__global__ void pool_partial(const int* __restrict__ batch, const u32* __restrict__ h3,
                             float* __restrict__ pooled, int* __restrict__ gcnt, int n) {
  int wave = threadIdx.x >> 6, lane = threadIdx.x & 63;
  int start = blockIdx.x * PB_NODES;
  int end = min(start + PB_NODES, n);
  float a0 = 0.f, a1 = 0.f;
  int gcur = -1, cnt = 0;
  for (int i = start + wave; i < end; i += 4) {
    int g = batch[i];
    if (g != gcur) {
      if (gcur >= 0) {
        atomicAdd(&pooled[gcur * 128 + lane * 2], a0);
        atomicAdd(&pooled[gcur * 128 + lane * 2 + 1], a1);
        if (lane == 0) atomicAdd(&gcnt[gcur], cnt);
      }
      gcur = g; a0 = 0.f; a1 = 0.f; cnt = 0;
    }
    u32 v = h3[(size_t)i * 64 + lane];
    a0 += bf2f(v & 0xFFFFu);
    a1 += bf2f(v >> 16);
    cnt++;
  }
  if (gcur >= 0) {
    atomicAdd(&pooled[gcur * 128 + lane * 2], a0);
    atomicAdd(&pooled[gcur * 128 + lane * 2 + 1], a1);
    if (lane == 0) atomicAdd(&gcnt[gcur], cnt);
  }
}

__global__ void head_kernel(const float* __restrict__ pooled, const int* __restrict__ gcnt,
                            const float* __restrict__ Wfc, const float* __restrict__ bfc,
                            float* __restrict__ out) {
  __shared__ float lg[64][10];
  int t = threadIdx.x;
  if (t < 640) {
    int g = t / 10, c = t % 10;
    float inv = 1.f / (float)max(gcnt[g], 1);
    float acc = bfc[c];
    for (int k = 0; k < 128; ++k) acc += pooled[g * 128 + k] * inv * Wfc[k * 10 + c];
    lg[g][c] = acc;
  }
  __syncthreads();
  if (t < 640) {
    int g = t / 10, c = t % 10;
    float mx = -1e30f;
    for (int q = 0; q < 10; ++q) mx = fmaxf(mx, lg[g][q]);
    float se = 0.f;
    for (int q = 0; q < 10; ++q) se += expf(lg[g][q] - mx);
    out[g * 10 + c] = lg[g][c] - mx - logf(se);
  }
}

extern "C" void kernel_launch(void* const* d_in, const int* in_sizes, int n_in,
                              void* d_out, int out_size, void* d_ws, size_t ws_size,
                              hipStream_t stream) {
  const float* x   = (const float*)d_in[0];
  const int* ei    = (const int*)d_in[1];
  const int* batch = (const int*)d_in[2];
  const float* W1l = (const float*)d_in[3];
  const float* W1r = (const float*)d_in[4];
  const float* b1  = (const float*)d_in[5];
  const float* W2l = (const float*)d_in[6];
  const float* W2r = (const float*)d_in[7];
  const float* b2  = (const float*)d_in[8];
  const float* W3l = (const float*)d_in[9];
  const float* W3r = (const float*)d_in[10];
  const float* b3  = (const float*)d_in[11];
  const float* Wfc = (const float*)d_in[12];
  const float* bfc = (const float*)d_in[13];
  float* out = (float*)d_out;
  int N = in_sizes[0];
  int E = in_sizes[1] / 2;
  const int* src = ei;
  const int* dst = ei + E;

  char* p = (char*)d_ws;
  auto alloc = [&](size_t bytes) { void* r = (void*)p; p += (bytes + 255) & ~(size_t)255; return r; };
  int* roff   = (int*)alloc((size_t)(N + 1) * 4);
  int* csr    = (int*)alloc((size_t)E * 4);
  float* mean1 = (float*)alloc((size_t)N * 4);
  u32* bufA   = (u32*)alloc((size_t)N * 64 * 4);  // h1 -> mean3 -> h3 (aliases hist early)
  u32* bufB   = (u32*)alloc((size_t)N * 64 * 4);  // mean2 -> h2      (aliases part early)
  u16* wt2    = (u16*)alloc(32768 * 2);
  u16* wt3    = (u16*)alloc(32768 * 2);
  float* pooled = (float*)alloc(64 * 128 * 4);
  int* gcnt   = (int*)alloc(64 * 4);
  int* bsum   = (int*)alloc(1024 * 4);

  // CSR-build-time aliases (strictly before h1/agg2 write bufA/bufB)
  int nbuk = (N + 127) >> 7;          // 782
  int* hist = (int*)bufA;             // nbuk*HBLK ints = 800 KB
  u32* part = (u32*)bufB;             // E u32 = 6.4 MB
  int chunk = (E + HBLK - 1) / HBLK;  // 6250
  int nH = nbuk * HBLK;               // 200192
  int nbH = (nH + 255) / 256;         // 782 <= 1024

  hipMemsetAsync(pooled, 0, 64 * 128 * 4, stream);
  hipMemsetAsync(gcnt, 0, 64 * 4, stream);
  hist_kernel<<<HBLK, 256, 0, stream>>>(dst, hist, E, nbuk, chunk);
  scan_local<<<nbH, 256, 0, stream>>>(hist, hist, bsum, nH);
  scan_bsum<<<1, 1024, 0, stream>>>(bsum, nbH);
  scan_add<<<nbH, 256, 0, stream>>>(hist, bsum, nH);
  scatter2_kernel<<<HBLK, 256, 0, stream>>>(src, dst, hist, part, E, nbuk, chunk);
  scatter3_kernel<<<nbuk, 256, 0, stream>>>(part, hist, roff, csr, E, nbuk, N);
  wprep_kernel<<<128, 256, 0, stream>>>(W2l, W2r, wt2);
  wprep_kernel<<<128, 256, 0, stream>>>(W3l, W3r, wt3);
  mean1_kernel<<<(N + 255) / 256, 256, 0, stream>>>(csr, roff, x, mean1, N);
  h1_kernel<<<((size_t)N * 64 + 255) / 256, 256, 0, stream>>>(mean1, x, W1l, W1r, b1, bufA, N);
  agg2_kernel<<<(N + 3) / 4, 256, 0, stream>>>(csr, roff, mean1, x, W1l, W1r, b1, bufB, N);
  mm_kernel<<<(N + 63) / 64, 256, 0, stream>>>((const u16*)bufB, (const u16*)bufA, wt2, b2, (u16*)bufB, N);
  agg3_kernel<<<(N + 3) / 4, 256, 0, stream>>>(csr, roff, bufB, bufA, N);
  mm_kernel<<<(N + 63) / 64, 256, 0, stream>>>((const u16*)bufA, (const u16*)bufB, wt3, b3, (u16*)bufA, N);
  pool_partial<<<(N + PB_NODES - 1) / PB_NODES, 256, 0, stream>>>(batch, bufA, pooled, gcnt, N);
  head_kernel<<<1, 640, 0, stream>>>(pooled, gcnt, Wfc, bfc, out);
}

// Round 5
// 408.123 us; speedup vs baseline: 2.6781x; 1.0318x over previous
//
#include <hip/hip_runtime.h>

typedef unsigned int u32;
typedef unsigned short u16;
typedef short bf16x8 __attribute__((ext_vector_type(8)));
typedef float f32x4 __attribute__((ext_vector_type(4)));
typedef u32 u32x4 __attribute__((ext_vector_type(4)));

#define HBLK 256  // blocks in hist/scatter2 pass

__device__ __forceinline__ u16 f2bf(float f) {
  u32 u = __float_as_uint(f);
  u = (u + 0x7FFFu + ((u >> 16) & 1u)) >> 16;
  return (u16)u;
}
__device__ __forceinline__ float bf2f(u32 h) { return __uint_as_float(h << 16); }

// ---------------- CSR build: bucket sort by dst ----------------
// bucket = dst >> 7 (128 nodes per bucket)
__global__ void hist_kernel(const int* __restrict__ dst, int* __restrict__ hist,
                            int E, int nbuk, int chunk) {
  __shared__ int h[1024];
  for (int i = threadIdx.x; i < nbuk; i += 256) h[i] = 0;
  __syncthreads();
  int b0 = blockIdx.x * chunk, b1 = min(b0 + chunk, E);
  for (int e = b0 + threadIdx.x; e < b1; e += 256)
    atomicAdd(&h[dst[e] >> 7], 1);
  __syncthreads();
  for (int i = threadIdx.x; i < nbuk; i += 256)
    hist[i * HBLK + blockIdx.x] = h[i];  // [bucket][block]
}

// generic parallel scan (exclusive), 3 launches
__global__ void scan_local(const int* __restrict__ in, int* __restrict__ out,
                           int* __restrict__ bsum, int n) {
  __shared__ int s[256];
  int tid = threadIdx.x;
  int i = blockIdx.x * 256 + tid;
  int v = (i < n) ? in[i] : 0;
  s[tid] = v;
  __syncthreads();
  for (int off = 1; off < 256; off <<= 1) {
    int t = (tid >= off) ? s[tid - off] : 0;
    __syncthreads();
    s[tid] += t;
    __syncthreads();
  }
  if (i < n) out[i] = s[tid] - v;  // local exclusive
  if (tid == 255) bsum[blockIdx.x] = s[255];
}

__global__ void scan_bsum(int* bsum, int nb) {
  __shared__ int s[1024];
  int tid = threadIdx.x;
  int v = (tid < nb) ? bsum[tid] : 0;
  s[tid] = v;
  __syncthreads();
  for (int off = 1; off < 1024; off <<= 1) {
    int t = (tid >= off) ? s[tid - off] : 0;
    __syncthreads();
    s[tid] += t;
    __syncthreads();
  }
  if (tid < nb) bsum[tid] = s[tid] - v;
}

__global__ void scan_add(int* __restrict__ a, const int* __restrict__ bsum, int n) {
  int i = blockIdx.x * 256 + threadIdx.x;
  if (i < n) a[i] += bsum[blockIdx.x];
}

// partition edges into bucket-ordered part[]: packed (dstLow7<<25 | src)
__global__ void scatter2_kernel(const int* __restrict__ src, const int* __restrict__ dst,
                                const int* __restrict__ hist_s, u32* __restrict__ part,
                                int E, int nbuk, int chunk) {
  __shared__ int cur[1024];
  for (int i = threadIdx.x; i < nbuk; i += 256)
    cur[i] = hist_s[i * HBLK + blockIdx.x];
  __syncthreads();
  int b0 = blockIdx.x * chunk, b1 = min(b0 + chunk, E);
  for (int e = b0 + threadIdx.x; e < b1; e += 256) {
    int d = dst[e];
    int pos = atomicAdd(&cur[d >> 7], 1);
    part[pos] = (u32)src[e] | ((u32)(d & 127) << 25);
  }
}

// per-bucket: count per node, scan -> roff, scatter src into contiguous csr window
__global__ void scatter3_kernel(const u32* __restrict__ part, const int* __restrict__ hist_s,
                                int* __restrict__ roff, int* __restrict__ csr,
                                int E, int nbuk, int n) {
  int b = blockIdx.x;
  int tid = threadIdx.x;
  int base = hist_s[b * HBLK];
  int end = (b + 1 < nbuk) ? hist_s[(b + 1) * HBLK] : E;
  __shared__ int cnt[128];
  __shared__ int s[128];
  __shared__ int cur[128];
  if (tid < 128) cnt[tid] = 0;
  __syncthreads();
  for (int e = base + tid; e < end; e += 256)
    atomicAdd(&cnt[part[e] >> 25], 1);
  __syncthreads();
  if (tid < 128) s[tid] = cnt[tid];
  __syncthreads();
  for (int off = 1; off < 128; off <<= 1) {
    int t = (tid >= off && tid < 128) ? s[tid - off] : 0;
    __syncthreads();
    if (tid < 128) s[tid] += t;
    __syncthreads();
  }
  if (tid < 128) {
    int excl = s[tid] - cnt[tid];
    cur[tid] = base + excl;
    int node = b * 128 + tid;
    if (node < n) roff[node] = base + excl;
  }
  if (b == 0 && tid == 0) roff[n] = E;
  __syncthreads();
  for (int e = base + tid; e < end; e += 256) {
    u32 p = part[e];
    int pos = atomicAdd(&cur[p >> 25], 1);
    csr[pos] = (int)(p & 0x1FFFFFFu);
  }
}

// ---------------- layer 1 (rank-2) ----------------
__global__ void mean1_kernel(const int* __restrict__ csr, const int* __restrict__ roff,
                             const float* __restrict__ x, float* __restrict__ mean1, int n) {
  int i = blockIdx.x * 256 + threadIdx.x;
  if (i >= n) return;
  int e0 = roff[i], e1 = roff[i + 1];
  float s = 0.f;
  for (int e = e0; e < e1; ++e) s += x[csr[e]];
  mean1[i] = s / (float)max(e1 - e0, 1);
}

__global__ void h1_kernel(const float* __restrict__ mean1, const float* __restrict__ x,
                          const float* __restrict__ W1l, const float* __restrict__ W1r,
                          const float* __restrict__ b1, u32* __restrict__ h1, int n) {
  int idx = blockIdx.x * 256 + threadIdx.x;  // over n*64 packed words
  if (idx >= n * 64) return;
  int i = idx >> 6, w = idx & 63;
  int j0 = w * 2;
  float m1 = mean1[i], xs = x[i];
  float v0 = fmaxf(m1 * W1l[j0] + xs * W1r[j0] + b1[j0], 0.f);
  float v1 = fmaxf(m1 * W1l[j0 + 1] + xs * W1r[j0 + 1] + b1[j0 + 1], 0.f);
  h1[idx] = (u32)f2bf(v0) | ((u32)f2bf(v1) << 16);
}

// generic mean-aggregation of bf16 feature rows over CSR.
// 4x16-lane groups each gather a different edge's 256B row via dwordx4;
// 4-deep unroll -> 16 edges in flight per wave (cascade 2-deep / 1-deep tail).
__global__ void agg_kernel(const int* __restrict__ csr, const int* __restrict__ roff,
                           const u32* __restrict__ hin, u32* __restrict__ outv, int n) {
  int wave = threadIdx.x >> 6, lane = threadIdx.x & 63;
  int i = blockIdx.x * 4 + wave;
  if (i >= n) return;
  int grp = lane >> 4, li = lane & 15;
  int e0 = roff[i], e1 = roff[i + 1];
  float a[8] = {};
  int e = e0 + grp;
  for (; e + 12 < e1; e += 16) {
    int s0 = csr[e], s1 = csr[e + 4], s2 = csr[e + 8], s3 = csr[e + 12];
    u32x4 v0 = *(const u32x4*)(hin + (size_t)s0 * 64 + li * 4);
    u32x4 v1 = *(const u32x4*)(hin + (size_t)s1 * 64 + li * 4);
    u32x4 v2 = *(const u32x4*)(hin + (size_t)s2 * 64 + li * 4);
    u32x4 v3 = *(const u32x4*)(hin + (size_t)s3 * 64 + li * 4);
#pragma unroll
    for (int w = 0; w < 4; ++w) {
      a[2 * w]     += bf2f(v0[w] & 0xFFFFu) + bf2f(v1[w] & 0xFFFFu) +
                      bf2f(v2[w] & 0xFFFFu) + bf2f(v3[w] & 0xFFFFu);
      a[2 * w + 1] += bf2f(v0[w] >> 16) + bf2f(v1[w] >> 16) +
                      bf2f(v2[w] >> 16) + bf2f(v3[w] >> 16);
    }
  }
  for (; e + 4 < e1; e += 8) {
    int s0 = csr[e], s1 = csr[e + 4];
    u32x4 v0 = *(const u32x4*)(hin + (size_t)s0 * 64 + li * 4);
    u32x4 v1 = *(const u32x4*)(hin + (size_t)s1 * 64 + li * 4);
#pragma unroll
    for (int w = 0; w < 4; ++w) {
      a[2 * w]     += bf2f(v0[w] & 0xFFFFu) + bf2f(v1[w] & 0xFFFFu);
      a[2 * w + 1] += bf2f(v0[w] >> 16) + bf2f(v1[w] >> 16);
    }
  }
  if (e < e1) {
    int s0 = csr[e];
    u32x4 v0 = *(const u32x4*)(hin + (size_t)s0 * 64 + li * 4);
#pragma unroll
    for (int w = 0; w < 4; ++w) {
      a[2 * w]     += bf2f(v0[w] & 0xFFFFu);
      a[2 * w + 1] += bf2f(v0[w] >> 16);
    }
  }
#pragma unroll
  for (int w = 0; w < 8; ++w) {
    a[w] += __shfl_xor(a[w], 16, 64);
    a[w] += __shfl_xor(a[w], 32, 64);
  }
  if (grp == 0) {
    float inv = 1.f / (float)max(e1 - e0, 1);
    u32x4 o;
#pragma unroll
    for (int w = 0; w < 4; ++w)
      o[w] = (u32)f2bf(a[2 * w] * inv) | ((u32)f2bf(a[2 * w + 1] * inv) << 16);
    *(u32x4*)(outv + (size_t)i * 64 + li * 4) = o;
  }
}

// pack [W_l; W_r] (256x128 f32, row-major k x j) into bf16 W^T layout wt[j][k], j<128, k<256
__global__ void wprep_kernel(const float* __restrict__ Wl, const float* __restrict__ Wr,
                             u16* __restrict__ wt) {
  int idx = blockIdx.x * 256 + threadIdx.x;  // 0..32767
  int j = idx >> 8, k = idx & 255;
  float v = (k < 128) ? Wl[k * 128 + j] : Wr[(k - 128) * 128 + j];
  wt[idx] = f2bf(v);
}

// h_next = relu([mean | h] @ [Wl; Wr] + b), MFMA 16x16x32 bf16, in-place safe (per-wave rows)
__launch_bounds__(256)
__global__ void mm_kernel(const u16* Aleft, const u16* Aright,
                          const u16* __restrict__ Wt, const float* __restrict__ bias,
                          u16* Out, int n) {
  __shared__ u16 wlds[32768];  // [j][256], 16B chunks XOR-swizzled by j
  for (int c = threadIdx.x; c < 4096; c += 256) {
    int j = c >> 5, ch = c & 31;
    int swz = ch ^ (j & 31);
    *(u32x4*)(&wlds[j * 256 + swz * 8]) = *(const u32x4*)(&Wt[j * 256 + ch * 8]);
  }
  __syncthreads();
  int wave = threadIdx.x >> 6;
  int lane = threadIdx.x & 63;
  int quad = lane >> 4, l16 = lane & 15;
  int row0 = blockIdx.x * 64 + wave * 16;
  int m = row0 + l16;
  int mc = m < n ? m : (n - 1);
  f32x4 acc[8] = {};
  const u16* Ah[2] = {Aleft, Aright};
#pragma unroll
  for (int half = 0; half < 2; ++half) {
    const u16* A = Ah[half] + (size_t)mc * 128;
#pragma unroll
    for (int s = 0; s < 4; ++s) {
      bf16x8 a = *(const bf16x8*)(A + s * 32 + quad * 8);
      int chunk = (half << 4) + (s << 2) + quad;
#pragma unroll
      for (int t = 0; t < 8; ++t) {
        int j = t * 16 + l16;
        int swz = chunk ^ (j & 31);
        bf16x8 b = *(const bf16x8*)(&wlds[j * 256 + swz * 8]);
        acc[t] = __builtin_amdgcn_mfma_f32_16x16x32_bf16(a, b, acc[t], 0, 0, 0);
      }
    }
  }
#pragma unroll
  for (int t = 0; t < 8; ++t) {
    int j = t * 16 + l16;
    float bj = bias[j];
#pragma unroll
    for (int r = 0; r < 4; ++r) {
      int mr = row0 + quad * 4 + r;
      if (mr < n) {
        float v = acc[t][r] + bj;
        Out[(size_t)mr * 128 + j] = f2bf(fmaxf(v, 0.f));
      }
    }
  }
}

// ---------------- pooling (two-phase, parallel) ----------------
#define PB_NODES 256
__global__ void pool_partial(const int* __restrict__ batch, const u32* __restrict__ h3,
                             float* __restrict__ pooled, int* __restrict__ gcnt, int n) {
  int wave = threadIdx.x >> 6, lane = threadIdx.x & 63;
  int start = blockIdx.x * PB_NODES;
  int end = min(start + PB_NODES, n);
  float a0 = 0.f, a1 = 0.f;
  int gcur = -1, cnt = 0;
  for (int i = start + wave; i < end; i += 4) {
    int g = batch[i];
    if (g != gcur) {
      if (gcur >= 0) {
        atomicAdd(&pooled[gcur * 128 + lane * 2], a0);
        atomicAdd(&pooled[gcur * 128 + lane * 2 + 1], a1);
        if (lane == 0) atomicAdd(&gcnt[gcur], cnt);
      }
      gcur = g; a0 = 0.f; a1 = 0.f; cnt = 0;
    }
    u32 v = h3[(size_t)i * 64 + lane];
    a0 += bf2f(v & 0xFFFFu);
    a1 += bf2f(v >> 16);
    cnt++;
  }
  if (gcur >= 0) {
    atomicAdd(&pooled[gcur * 128 + lane * 2], a0);
    atomicAdd(&pooled[gcur * 128 + lane * 2 + 1], a1);
    if (lane == 0) atomicAdd(&gcnt[gcur], cnt);
  }
}

__global__ void head_kernel(const float* __restrict__ pooled, const int* __restrict__ gcnt,
                            const float* __restrict__ Wfc, const float* __restrict__ bfc,
                            float* __restrict__ out) {
  __shared__ float lg[64][10];
  int t = threadIdx.x;
  if (t < 640) {
    int g = t / 10, c = t % 10;
    float inv = 1.f / (float)max(gcnt[g], 1);
    float acc = bfc[c];
    for (int k = 0; k < 128; ++k) acc += pooled[g * 128 + k] * inv * Wfc[k * 10 + c];
    lg[g][c] = acc;
  }
  __syncthreads();
  if (t < 640) {
    int g = t / 10, c = t % 10;
    float mx = -1e30f;
    for (int q = 0; q < 10; ++q) mx = fmaxf(mx, lg[g][q]);
    float se = 0.f;
    for (int q = 0; q < 10; ++q) se += expf(lg[g][q] - mx);
    out[g * 10 + c] = lg[g][c] - mx - logf(se);
  }
}

extern "C" void kernel_launch(void* const* d_in, const int* in_sizes, int n_in,
                              void* d_out, int out_size, void* d_ws, size_t ws_size,
                              hipStream_t stream) {
  const float* x   = (const float*)d_in[0];
  const int* ei    = (const int*)d_in[1];
  const int* batch = (const int*)d_in[2];
  const float* W1l = (const float*)d_in[3];
  const float* W1r = (const float*)d_in[4];
  const float* b1  = (const float*)d_in[5];
  const float* W2l = (const float*)d_in[6];
  const float* W2r = (const float*)d_in[7];
  const float* b2  = (const float*)d_in[8];
  const float* W3l = (const float*)d_in[9];
  const float* W3r = (const float*)d_in[10];
  const float* b3  = (const float*)d_in[11];
  const float* Wfc = (const float*)d_in[12];
  const float* bfc = (const float*)d_in[13];
  float* out = (float*)d_out;
  int N = in_sizes[0];
  int E = in_sizes[1] / 2;
  const int* src = ei;
  const int* dst = ei + E;

  char* p = (char*)d_ws;
  auto alloc = [&](size_t bytes) { void* r = (void*)p; p += (bytes + 255) & ~(size_t)255; return r; };
  int* roff   = (int*)alloc((size_t)(N + 1) * 4);
  int* csr    = (int*)alloc((size_t)E * 4);
  float* mean1 = (float*)alloc((size_t)N * 4);
  u32* bufA   = (u32*)alloc((size_t)N * 64 * 4);  // h1 -> mean3 -> h3 (aliases hist early)
  u32* bufB   = (u32*)alloc((size_t)N * 64 * 4);  // mean2 -> h2      (aliases part early)
  u16* wt2    = (u16*)alloc(32768 * 2);
  u16* wt3    = (u16*)alloc(32768 * 2);
  float* pooled = (float*)alloc(64 * 128 * 4);
  int* gcnt   = (int*)alloc(64 * 4);
  int* bsum   = (int*)alloc(1024 * 4);

  // CSR-build-time aliases (strictly before h1/agg write bufA/bufB)
  int nbuk = (N + 127) >> 7;          // 782
  int* hist = (int*)bufA;             // nbuk*HBLK ints = 800 KB
  u32* part = (u32*)bufB;             // E u32 = 6.4 MB
  int chunk = (E + HBLK - 1) / HBLK;  // 6250
  int nH = nbuk * HBLK;               // 200192
  int nbH = (nH + 255) / 256;         // 782 <= 1024

  hipMemsetAsync(pooled, 0, 64 * 128 * 4, stream);
  hipMemsetAsync(gcnt, 0, 64 * 4, stream);
  hist_kernel<<<HBLK, 256, 0, stream>>>(dst, hist, E, nbuk, chunk);
  scan_local<<<nbH, 256, 0, stream>>>(hist, hist, bsum, nH);
  scan_bsum<<<1, 1024, 0, stream>>>(bsum, nbH);
  scan_add<<<nbH, 256, 0, stream>>>(hist, bsum, nH);
  scatter2_kernel<<<HBLK, 256, 0, stream>>>(src, dst, hist, part, E, nbuk, chunk);
  scatter3_kernel<<<nbuk, 256, 0, stream>>>(part, hist, roff, csr, E, nbuk, N);
  wprep_kernel<<<128, 256, 0, stream>>>(W2l, W2r, wt2);
  wprep_kernel<<<128, 256, 0, stream>>>(W3l, W3r, wt3);
  mean1_kernel<<<(N + 255) / 256, 256, 0, stream>>>(csr, roff, x, mean1, N);
  h1_kernel<<<((size_t)N * 64 + 255) / 256, 256, 0, stream>>>(mean1, x, W1l, W1r, b1, bufA, N);
  agg_kernel<<<(N + 3) / 4, 256, 0, stream>>>(csr, roff, bufA, bufB, N);   // mean2 = agg(h1)
  mm_kernel<<<(N + 63) / 64, 256, 0, stream>>>((const u16*)bufB, (const u16*)bufA, wt2, b2, (u16*)bufB, N);
  agg_kernel<<<(N + 3) / 4, 256, 0, stream>>>(csr, roff, bufB, bufA, N);   // mean3 = agg(h2)
  mm_kernel<<<(N + 63) / 64, 256, 0, stream>>>((const u16*)bufA, (const u16*)bufB, wt3, b3, (u16*)bufA, N);
  pool_partial<<<(N + PB_NODES - 1) / PB_NODES, 256, 0, stream>>>(batch, bufA, pooled, gcnt, N);
  head_kernel<<<1, 640, 0, stream>>>(pooled, gcnt, Wfc, bfc, out);
}